// Round 6
// baseline (219.161 us; speedup 1.0000x reference)
//
#include <hip/hip_runtime.h>
#include <hip/hip_fp16.h>

#define P_PLANE (1080*1920)          // 2,073,600 pixels per channel plane
#define LUT_C   35937                 // 33*33*33, per-channel LUT stride
#define N_IMG   4
#define SMEM_WORDS 35937
#define SMEM_BYTES (SMEM_WORDS * 4)   // 143,748 B of LDS

// Work decomposition: quad = 4 consecutive pixels; group = 64 quads (one per
// lane of a wave) = 1KB per plane per load instr. 2,073,600 quads / 64 =
// 32,400 groups; 8,100 groups per image (no group straddles an image).
#define QPI        (P_PLANE / 4)      // 518,400 quads per image
#define TOTAL_Q    (N_IMG * QPI)      // 2,073,600
#define N_GROUPS   (TOTAL_Q / 64)     // 32,400
#define GRP_PER_IMG (QPI / 64)        // 8,100
#define N_CTR      8                  // distributed ticket counters
#define SPAN       (N_GROUPS / N_CTR) // 4,050 groups per counter
#define CTR_WORD0  36000              // counters live at ws word 36000 (byte 144,000)
#define CTR_STRIDE 64                 // 64 words = 256B between counters
#define WS_NEEDED  (CTR_WORD0*4 + N_CTR*CTR_STRIDE*4)

typedef float fvec4 __attribute__((ext_vector_type(4)));   // builtin-compatible float4

__device__ __forceinline__ float ub0(unsigned int e) { return (float)(e & 255u); }
__device__ __forceinline__ float ub1(unsigned int e) { return (float)((e >> 8) & 255u); }
__device__ __forceinline__ float ub2(unsigned int e) { return (float)((e >> 16) & 255u); }

// ---------------------------------------------------------------------------
// Build linear u8 table in ws + zero the 8 work-stealing counters.
// Entry i (= b*1089+g*33+r) packs (r,g,b,0) u8. 140.4 KB.
// ---------------------------------------------------------------------------
__global__ __launch_bounds__(256) void build_lin_u8(const float* __restrict__ lut,
                                                    unsigned int* __restrict__ ws) {
    int i = blockIdx.x * blockDim.x + threadIdx.x;
    if (blockIdx.x == 0 && threadIdx.x < N_CTR)
        ws[CTR_WORD0 + threadIdx.x * CTR_STRIDE] = 0u;   // ticket counters
    if (i >= LUT_C) return;
    unsigned int r = (unsigned int)__float2int_rn(lut[i] * 255.0f);
    unsigned int g = (unsigned int)__float2int_rn(lut[LUT_C + i] * 255.0f);
    unsigned int b = (unsigned int)__float2int_rn(lut[2 * LUT_C + i] * 255.0f);
    ws[i] = r | (g << 8) | (b << 16);
}

// ---------------------------------------------------------------------------
// R6 main kernel: full LUT (u8x4) in LDS (structure proven R0/R2/R5, all
// 63-66us) + WAVE-LEVEL WORK-STEALING to kill the suspected serial-tail:
// grid==CU-count with a 1-block/CU LDS cap means ONE unavailable/doubled CU
// serializes a whole second block while 255 CUs idle (occupancy measured 33%
// vs 50% expected; inner-schedule changes R2/R4/R5 all invisible). Waves pull
// 64-quad groups from 8 distributed atomic counters (blockIdx&7, 256B apart;
// 32 blocks share each counter) so a slow CU just grabs fewer groups.
// Ticket atomic issues before the DS phase, is consumed after it; next
// group's loads prefetch with a full compute phase to land.
// ---------------------------------------------------------------------------
__global__ __launch_bounds__(1024, 4) void apply_lut_lds(const float* __restrict__ x,
                                                         const unsigned int* __restrict__ T,
                                                         unsigned int* __restrict__ ctrs,
                                                         float* __restrict__ out) {
    extern __shared__ unsigned int s_lut[];
    const int tid = threadIdx.x;

    // Fill LDS: 8984 uint4 + 1 tail word, coalesced.
    {
        const uint4* Tv = (const uint4*)T;
        uint4* sv = (uint4*)s_lut;
        for (int i = tid; i < SMEM_WORDS / 4; i += blockDim.x) sv[i] = Tv[i];
        if (tid == 0) s_lut[SMEM_WORDS - 1] = T[SMEM_WORDS - 1];
    }
    __syncthreads();

    const float inv = (float)(1.0 / (1.000001 / 32.0));   // matches reference f32 rounding
    const float qs = 1.0f / 255.0f;                        // u8 dequant, folded into wb
    const int lane = tid & 63;
    const int c = blockIdx.x & (N_CTR - 1);
    unsigned int* myctr = ctrs + c * CTR_STRIDE;
    const int gbase = c * SPAN;

    // ---- Prologue: first ticket (synchronous) + its loads.
    int t;
    {
        unsigned int tv = 0u;
        if (lane == 0) tv = atomicAdd(myctr, 1u);
        t = __builtin_amdgcn_readfirstlane((int)tv);
    }
    if (t >= SPAN) return;

    size_t base;
    {
        int g = gbase + t;
        int n = g / GRP_PER_IMG;
        base = (size_t)n * (3 * P_PLANE) + (size_t)(g - n * GRP_PER_IMG) * 256 + lane * 4;
    }
    fvec4 r4 = *(const fvec4*)(x + base);
    fvec4 g4 = *(const fvec4*)(x + base + P_PLANE);
    fvec4 b4 = *(const fvec4*)(x + base + 2 * P_PLANE);

    while (true) {
        // ---- Phase 0: fire next ticket (consumed after Phase B; latency
        // hidden under idx + DS phases).
        unsigned int tv = 0u;
        if (lane == 0) tv = atomicAdd(myctr, 1u);

        // ---- Phase A: idx + fracs for 4 pixels (consumes current loads).
        int   idx[4];
        float fr[4], fg[4], fb[4];
#pragma unroll
        for (int i = 0; i < 4; ++i) {
            float tr = r4[i] * inv, tg = g4[i] * inv, tb = b4[i] * inv;
            float fr_ = floorf(tr), fg_ = floorf(tg), fb_ = floorf(tb);
            fr[i] = tr - fr_; fg[i] = tg - fg_; fb[i] = tb - fb_;   // fracs BEFORE clip
            int ri = min(max((int)fr_, 0), 31);
            int gi = min(max((int)fg_, 0), 31);
            int bi = min(max((int)fb_, 0), 31);
            idx[i] = bi * 1089 + gi * 33 + ri;
        }

        // ---- Phase B: issue all 16 ds_read2-class gathers.
        unsigned int e[4][8];
#pragma unroll
        for (int i = 0; i < 4; ++i) {
            int i0 = idx[i];
            int i1 = idx[i] + 1089;
            e[i][0] = s_lut[i0];       e[i][1] = s_lut[i0 + 1];
            e[i][2] = s_lut[i0 + 33];  e[i][3] = s_lut[i0 + 34];
            e[i][4] = s_lut[i1];       e[i][5] = s_lut[i1 + 1];
            e[i][6] = s_lut[i1 + 33];  e[i][7] = s_lut[i1 + 34];
        }

        // ---- Phase C: consume ticket; prefetch next group's loads (they get
        // phases D-F plus next Phase A to land).
        int tn = __builtin_amdgcn_readfirstlane((int)tv);
        const bool more = (tn < SPAN);
        size_t nbase;
        {
            int g = gbase + (more ? tn : t);     // tail: re-read own group (L1-hot)
            int n = g / GRP_PER_IMG;
            nbase = (size_t)n * (3 * P_PLANE) + (size_t)(g - n * GRP_PER_IMG) * 256 + lane * 4;
        }
        fvec4 nr4 = *(const fvec4*)(x + nbase);
        fvec4 ng4 = *(const fvec4*)(x + nbase + P_PLANE);
        fvec4 nb4 = *(const fvec4*)(x + nbase + 2 * P_PLANE);

        // ---- FENCE: keep issue phases above, consume phases below.
        __builtin_amdgcn_sched_barrier(0);

        // ---- Phase D: weights (pure VALU, fills the DS shadow).
        float w[4][8];
#pragma unroll
        for (int i = 0; i < 4; ++i) {
            float wr1 = fr[i], wr0 = 1.0f - fr[i];
            float wg1 = fg[i], wg0 = 1.0f - fg[i];
            float wb1 = fb[i] * qs, wb0 = (1.0f - fb[i]) * qs;   // fold 1/255
            float w00 = wb0 * wg0, w01 = wb0 * wg1, w10 = wb1 * wg0, w11 = wb1 * wg1;
            w[i][0] = w00 * wr0; w[i][1] = w00 * wr1;
            w[i][2] = w01 * wr0; w[i][3] = w01 * wr1;
            w[i][4] = w10 * wr0; w[i][5] = w10 * wr1;
            w[i][6] = w11 * wr0; w[i][7] = w11 * wr1;
        }

        // ---- Phase E: interpolate.
        fvec4 vR, vG, vB;
#pragma unroll
        for (int i = 0; i < 4; ++i) {
            float aR = w[i][0] * ub0(e[i][0]);
            float aG = w[i][0] * ub1(e[i][0]);
            float aB = w[i][0] * ub2(e[i][0]);
#pragma unroll
            for (int k = 1; k < 8; ++k) {
                aR = fmaf(w[i][k], ub0(e[i][k]), aR);
                aG = fmaf(w[i][k], ub1(e[i][k]), aG);
                aB = fmaf(w[i][k], ub2(e[i][k]), aB);
            }
            vR[i] = aR; vG[i] = aG; vB[i] = aB;
        }

        // ---- Phase F: coalesced nontemporal stores (1KB/wave each).
        __builtin_nontemporal_store(vR, (fvec4*)(out + base));
        __builtin_nontemporal_store(vG, (fvec4*)(out + base + P_PLANE));
        __builtin_nontemporal_store(vB, (fvec4*)(out + base + 2 * P_PLANE));

        if (!more) break;
        t = tn; base = nbase;
        r4 = nr4; g4 = ng4; b4 = nb4;
    }
}

// ===========================================================================
// Fallback path (R0, proven): fp16 cell-duplicated table + global gathers.
// ===========================================================================
__global__ __launch_bounds__(256) void build_table(const float* __restrict__ lut,
                                                   uint4* __restrict__ T) {
    int cell = blockIdx.x * blockDim.x + threadIdx.x;   // 0 .. 32767
    int rid = cell & 31;
    int gid = (cell >> 5) & 31;
    int bid = cell >> 10;
    const float* b0 = lut + bid * 1089 + gid * 33 + rid;
    uint4 q[4];
    __half* h = (__half*)q;
#pragma unroll
    for (int k = 0; k < 8; ++k) {
        int off = (k >> 2) * 1089 + ((k >> 1) & 1) * 33 + (k & 1);
        h[k * 4 + 0] = __float2half(b0[off]);
        h[k * 4 + 1] = __float2half(b0[LUT_C + off]);
        h[k * 4 + 2] = __float2half(b0[2 * LUT_C + off]);
        h[k * 4 + 3] = __float2half(0.0f);
    }
    uint4* dst = T + (size_t)cell * 4;
    dst[0] = q[0]; dst[1] = q[1]; dst[2] = q[2]; dst[3] = q[3];
}

__device__ __forceinline__ void acc_chunk(const uint4& q, float wA, float wB,
                                          float& aR, float& aG, float& aB) {
    const __half* h = (const __half*)&q;
    aR = fmaf(wA, __half2float(h[0]), fmaf(wB, __half2float(h[4]), aR));
    aG = fmaf(wA, __half2float(h[1]), fmaf(wB, __half2float(h[5]), aG));
    aB = fmaf(wA, __half2float(h[2]), fmaf(wB, __half2float(h[6]), aB));
}

__global__ __launch_bounds__(256) void apply_lut(const float* __restrict__ x,
                                                 const __half* __restrict__ T,
                                                 float* __restrict__ out) {
    const float inv = (float)(1.0 / (1.000001 / 32.0));
    int n  = blockIdx.y;
    int i4 = blockIdx.x * blockDim.x + threadIdx.x;
    size_t base = (size_t)n * 3 * P_PLANE + (size_t)i4 * 4;

    float4 r4 = *(const float4*)(x + base);
    float4 g4 = *(const float4*)(x + base + P_PLANE);
    float4 b4 = *(const float4*)(x + base + 2 * P_PLANE);

    float r[4] = {r4.x, r4.y, r4.z, r4.w};
    float g[4] = {g4.x, g4.y, g4.z, g4.w};
    float b[4] = {b4.x, b4.y, b4.z, b4.w};
    float oR[4], oG[4], oB[4];

#pragma unroll
    for (int i = 0; i < 4; ++i) {
        float tr = r[i] * inv;
        float tg = g[i] * inv;
        float tb = b[i] * inv;
        float fr_ = floorf(tr), fg_ = floorf(tg), fb_ = floorf(tb);
        float fr = tr - fr_, fg = tg - fg_, fb = tb - fb_;
        int ri = min(max((int)fr_, 0), 31);
        int gi = min(max((int)fg_, 0), 31);
        int bi = min(max((int)fb_, 0), 31);

        const uint4* cp = (const uint4*)(T + ((size_t)(((bi << 5) | gi) << 5 | ri) << 5));
        uint4 q0 = cp[0], q1 = cp[1], q2 = cp[2], q3 = cp[3];

        float wr1 = fr, wr0 = 1.0f - fr;
        float wg1 = fg, wg0 = 1.0f - fg;
        float wb1 = fb, wb0 = 1.0f - fb;
        float w00 = wb0 * wg0, w01 = wb0 * wg1, w10 = wb1 * wg0, w11 = wb1 * wg1;

        float aR = 0.f, aG = 0.f, aB = 0.f;
        acc_chunk(q0, w00 * wr0, w00 * wr1, aR, aG, aB);
        acc_chunk(q1, w01 * wr0, w01 * wr1, aR, aG, aB);
        acc_chunk(q2, w10 * wr0, w10 * wr1, aR, aG, aB);
        acc_chunk(q3, w11 * wr0, w11 * wr1, aR, aG, aB);

        oR[i] = aR; oG[i] = aG; oB[i] = aB;
    }

    *(float4*)(out + base)               = make_float4(oR[0], oR[1], oR[2], oR[3]);
    *(float4*)(out + base + P_PLANE)     = make_float4(oG[0], oG[1], oG[2], oG[3]);
    *(float4*)(out + base + 2 * P_PLANE) = make_float4(oB[0], oB[1], oB[2], oB[3]);
}

extern "C" void kernel_launch(void* const* d_in, const int* in_sizes, int n_in,
                              void* d_out, int out_size, void* d_ws, size_t ws_size,
                              hipStream_t stream) {
    const float* lut = (const float*)d_in[0];
    const float* x   = (const float*)d_in[1];
    float* out = (float*)d_out;

    // Capture-safe host-side queries — cached so repeated kernel_launch calls
    // don't pay the runtime-API cost per invocation.
    static int max_shm = -1;
    if (max_shm < 0) {
        int dev = 0;
        (void)hipGetDevice(&dev);
        (void)hipDeviceGetAttribute(&max_shm, hipDeviceAttributeMaxSharedMemoryPerBlock, dev);
        static_assert(SMEM_BYTES == 143748, "lut lds size");
        static_assert(N_GROUPS == 32400 && SPAN * N_CTR == N_GROUPS, "group math");
        (void)hipFuncSetAttribute((const void*)apply_lut_lds,
                                  hipFuncAttributeMaxDynamicSharedMemorySize, SMEM_BYTES);
        if (max_shm < 0) max_shm = 0;
    }

    if (max_shm >= SMEM_BYTES && ws_size >= (size_t)WS_NEEDED) {
        // LDS-resident linear u8 table; 256 persistent blocks x 1024 threads
        // (1 block/CU, LDS-capped); wave-level work stealing over 8 counters.
        unsigned int* ws = (unsigned int*)d_ws;
        build_lin_u8<<<(LUT_C + 255) / 256, 256, 0, stream>>>(lut, ws);
        apply_lut_lds<<<256, 1024, SMEM_BYTES, stream>>>(x, ws, ws + CTR_WORD0, out);
    } else {
        __half* T = (__half*)d_ws;
        build_table<<<128, 256, 0, stream>>>(lut, (uint4*)T);
        apply_lut<<<dim3(P_PLANE / (4 * 256), N_IMG), 256, 0, stream>>>(x, T, out);
    }
}

// Round 9
// 187.984 us; speedup vs baseline: 1.1658x; 1.1658x over previous
//
#include <hip/hip_runtime.h>
#include <hip/hip_fp16.h>

#define P_PLANE (1080*1920)          // 2,073,600 pixels per channel plane
#define LUT_C   35937                 // 33*33*33, per-channel LUT stride
#define N_IMG   4
#define SMEM_WORDS 35937
#define SMEM_BYTES (SMEM_WORDS * 4)   // 143,748 B of LDS

typedef float fvec4 __attribute__((ext_vector_type(4)));   // builtin-compatible float4

__device__ __forceinline__ float ub0(unsigned int e) { return (float)(e & 255u); }
__device__ __forceinline__ float ub1(unsigned int e) { return (float)((e >> 8) & 255u); }
__device__ __forceinline__ float ub2(unsigned int e) { return (float)((e >> 16) & 255u); }

// ---------------------------------------------------------------------------
// Build linear u8 table in ws: entry i (= b*1089+g*33+r) packs (r,g,b,0) u8.
// 35937 entries * 4B = 140.4 KB. Quantization err <= 1/510 ~ 2e-3.
// ---------------------------------------------------------------------------
__global__ __launch_bounds__(256) void build_lin_u8(const float* __restrict__ lut,
                                                    unsigned int* __restrict__ T) {
    int i = blockIdx.x * blockDim.x + threadIdx.x;
    if (i >= LUT_C) return;
    unsigned int r = (unsigned int)__float2int_rn(lut[i] * 255.0f);
    unsigned int g = (unsigned int)__float2int_rn(lut[LUT_C + i] * 255.0f);
    unsigned int b = (unsigned int)__float2int_rn(lut[2 * LUT_C + i] * 255.0f);
    T[i] = r | (g << 8) | (b << 16);
}

// ---------------------------------------------------------------------------
// R7 ablation, third submission (rounds 7/8 were broker/container failures —
// the experiment never ran). Kernel body identical to the R5 kernel (proven
// 63-66us) with ONE variable changed: plain stores instead of
// __builtin_nontemporal_store. Launcher reverted to the R0-proven stateless
// form to exclude the static-cache as a failure source.
// Store-drain theory: ~19K cy/wave-iteration observed vs ~2.5K cy critical
// path; 12KB NT stores/wave-iter at the measured ~1.53 TB/s drain = ~19K cy.
// NT (no-allocate) stores ack deep in the memory system; next iteration's
// output-register reuse forces a tail s_waitcnt on store drain. Plain stores
// ack at L2 and write back asynchronously. L2 eviction of streamed data is
// harmless (only the 144KB T array is reused, once, at kernel start).
// ---------------------------------------------------------------------------
__global__ __launch_bounds__(1024, 4) void apply_lut_lds(const float* __restrict__ x,
                                                         const unsigned int* __restrict__ T,
                                                         float* __restrict__ out) {
    extern __shared__ unsigned int s_lut[];
    const int tid = threadIdx.x;

    // Fill LDS: 8984 uint4 + 1 tail word, coalesced.
    {
        const uint4* Tv = (const uint4*)T;
        uint4* sv = (uint4*)s_lut;
        for (int i = tid; i < SMEM_WORDS / 4; i += blockDim.x) sv[i] = Tv[i];
        if (tid == 0) s_lut[SMEM_WORDS - 1] = T[SMEM_WORDS - 1];
    }
    __syncthreads();

    const float inv = (float)(1.0 / (1.000001 / 32.0));   // matches reference f32 rounding
    const float qs = 1.0f / 255.0f;                        // u8 dequant, folded into wb
    const int QPI = P_PLANE / 4;                           // 518,400 quads per image
    const int total = N_IMG * QPI;                         // 2,073,600 quads
    const int G = gridDim.x * blockDim.x;                  // 262,144

    int q = blockIdx.x * blockDim.x + tid;
    if (q >= total) return;

    size_t base;
    {
        int n = q / QPI;
        base = (size_t)n * (3 * P_PLANE) + (size_t)(q - n * QPI) * 4;
    }
    fvec4 r4 = *(const fvec4*)(x + base);
    fvec4 g4 = *(const fvec4*)(x + base + P_PLANE);
    fvec4 b4 = *(const fvec4*)(x + base + 2 * P_PLANE);

    while (true) {
        // ---- Phase A: idx + fracs for 4 pixels (consumes current loads).
        int   idx[4];
        float fr[4], fg[4], fb[4];
#pragma unroll
        for (int i = 0; i < 4; ++i) {
            float tr = r4[i] * inv, tg = g4[i] * inv, tb = b4[i] * inv;
            float fr_ = floorf(tr), fg_ = floorf(tg), fb_ = floorf(tb);
            fr[i] = tr - fr_; fg[i] = tg - fg_; fb[i] = tb - fb_;   // fracs BEFORE clip
            int ri = min(max((int)fr_, 0), 31);
            int gi = min(max((int)fg_, 0), 31);
            int bi = min(max((int)fb_, 0), 31);
            idx[i] = bi * 1089 + gi * 33 + ri;
        }

        // ---- Phase B: issue ALL 16 ds_read2-class gathers (32 dwords live).
        unsigned int e[4][8];
#pragma unroll
        for (int i = 0; i < 4; ++i) {
            int i0 = idx[i];
            int i1 = idx[i] + 1089;
            e[i][0] = s_lut[i0];       e[i][1] = s_lut[i0 + 1];
            e[i][2] = s_lut[i0 + 33];  e[i][3] = s_lut[i0 + 34];
            e[i][4] = s_lut[i1];       e[i][5] = s_lut[i1 + 1];
            e[i][6] = s_lut[i1 + 33];  e[i][7] = s_lut[i1 + 34];
        }

        // ---- Phase C: issue NEXT iteration's global loads (in the DS shadow).
        int qn = q + G;
        const bool more = (qn < total);
        int qc = more ? qn : q;                 // branchless tail: re-read q (L1-hot)
        size_t nbase;
        {
            int n = qc / QPI;
            nbase = (size_t)n * (3 * P_PLANE) + (size_t)(qc - n * QPI) * 4;
        }
        fvec4 nr4 = *(const fvec4*)(x + nbase);
        fvec4 ng4 = *(const fvec4*)(x + nbase + P_PLANE);
        fvec4 nb4 = *(const fvec4*)(x + nbase + 2 * P_PLANE);

        // ---- FENCE: keep issue phases above, consume phases below.
        __builtin_amdgcn_sched_barrier(0);

        // ---- Phase D: weights (pure VALU, fills the DS shadow).
        float w[4][8];
#pragma unroll
        for (int i = 0; i < 4; ++i) {
            float wr1 = fr[i], wr0 = 1.0f - fr[i];
            float wg1 = fg[i], wg0 = 1.0f - fg[i];
            float wb1 = fb[i] * qs, wb0 = (1.0f - fb[i]) * qs;   // fold 1/255
            float w00 = wb0 * wg0, w01 = wb0 * wg1, w10 = wb1 * wg0, w11 = wb1 * wg1;
            w[i][0] = w00 * wr0; w[i][1] = w00 * wr1;
            w[i][2] = w01 * wr0; w[i][3] = w01 * wr1;
            w[i][4] = w10 * wr0; w[i][5] = w10 * wr1;
            w[i][6] = w11 * wr0; w[i][7] = w11 * wr1;
        }

        // ---- Phase E: interpolate (ONE lgkm wait, then 96 FMAs).
        fvec4 vR, vG, vB;
#pragma unroll
        for (int i = 0; i < 4; ++i) {
            float aR = w[i][0] * ub0(e[i][0]);
            float aG = w[i][0] * ub1(e[i][0]);
            float aB = w[i][0] * ub2(e[i][0]);
#pragma unroll
            for (int k = 1; k < 8; ++k) {
                aR = fmaf(w[i][k], ub0(e[i][k]), aR);
                aG = fmaf(w[i][k], ub1(e[i][k]), aG);
                aB = fmaf(w[i][k], ub2(e[i][k]), aB);
            }
            vR[i] = aR; vG[i] = aG; vB[i] = aB;
        }

        // ---- Phase F: coalesced PLAIN stores (1KB/wave each; ack at L2).
        *(fvec4*)(out + base)               = vR;
        *(fvec4*)(out + base + P_PLANE)     = vG;
        *(fvec4*)(out + base + 2 * P_PLANE) = vB;

        if (!more) break;
        q = qn; base = nbase;
        r4 = nr4; g4 = ng4; b4 = nb4;
    }
}

// ===========================================================================
// Fallback path (R0, proven): fp16 cell-duplicated table + global gathers.
// ===========================================================================
__global__ __launch_bounds__(256) void build_table(const float* __restrict__ lut,
                                                   uint4* __restrict__ T) {
    int cell = blockIdx.x * blockDim.x + threadIdx.x;   // 0 .. 32767
    int rid = cell & 31;
    int gid = (cell >> 5) & 31;
    int bid = cell >> 10;
    const float* b0 = lut + bid * 1089 + gid * 33 + rid;
    uint4 q[4];
    __half* h = (__half*)q;
#pragma unroll
    for (int k = 0; k < 8; ++k) {
        int off = (k >> 2) * 1089 + ((k >> 1) & 1) * 33 + (k & 1);
        h[k * 4 + 0] = __float2half(b0[off]);
        h[k * 4 + 1] = __float2half(b0[LUT_C + off]);
        h[k * 4 + 2] = __float2half(b0[2 * LUT_C + off]);
        h[k * 4 + 3] = __float2half(0.0f);
    }
    uint4* dst = T + (size_t)cell * 4;
    dst[0] = q[0]; dst[1] = q[1]; dst[2] = q[2]; dst[3] = q[3];
}

__device__ __forceinline__ void acc_chunk(const uint4& q, float wA, float wB,
                                          float& aR, float& aG, float& aB) {
    const __half* h = (const __half*)&q;
    aR = fmaf(wA, __half2float(h[0]), fmaf(wB, __half2float(h[4]), aR));
    aG = fmaf(wA, __half2float(h[1]), fmaf(wB, __half2float(h[5]), aG));
    aB = fmaf(wA, __half2float(h[2]), fmaf(wB, __half2float(h[6]), aB));
}

__global__ __launch_bounds__(256) void apply_lut(const float* __restrict__ x,
                                                 const __half* __restrict__ T,
                                                 float* __restrict__ out) {
    const float inv = (float)(1.0 / (1.000001 / 32.0));
    int n  = blockIdx.y;
    int i4 = blockIdx.x * blockDim.x + threadIdx.x;
    size_t base = (size_t)n * 3 * P_PLANE + (size_t)i4 * 4;

    float4 r4 = *(const float4*)(x + base);
    float4 g4 = *(const float4*)(x + base + P_PLANE);
    float4 b4 = *(const float4*)(x + base + 2 * P_PLANE);

    float r[4] = {r4.x, r4.y, r4.z, r4.w};
    float g[4] = {g4.x, g4.y, g4.z, g4.w};
    float b[4] = {b4.x, b4.y, b4.z, b4.w};
    float oR[4], oG[4], oB[4];

#pragma unroll
    for (int i = 0; i < 4; ++i) {
        float tr = r[i] * inv;
        float tg = g[i] * inv;
        float tb = b[i] * inv;
        float fr_ = floorf(tr), fg_ = floorf(tg), fb_ = floorf(tb);
        float fr = tr - fr_, fg = tg - fg_, fb = tb - fb_;
        int ri = min(max((int)fr_, 0), 31);
        int gi = min(max((int)fg_, 0), 31);
        int bi = min(max((int)fb_, 0), 31);

        const uint4* cp = (const uint4*)(T + ((size_t)(((bi << 5) | gi) << 5 | ri) << 5));
        uint4 q0 = cp[0], q1 = cp[1], q2 = cp[2], q3 = cp[3];

        float wr1 = fr, wr0 = 1.0f - fr;
        float wg1 = fg, wg0 = 1.0f - fg;
        float wb1 = fb, wb0 = 1.0f - fb;
        float w00 = wb0 * wg0, w01 = wb0 * wg1, w10 = wb1 * wg0, w11 = wb1 * wg1;

        float aR = 0.f, aG = 0.f, aB = 0.f;
        acc_chunk(q0, w00 * wr0, w00 * wr1, aR, aG, aB);
        acc_chunk(q1, w01 * wr0, w01 * wr1, aR, aG, aB);
        acc_chunk(q2, w10 * wr0, w10 * wr1, aR, aG, aB);
        acc_chunk(q3, w11 * wr0, w11 * wr1, aR, aG, aB);

        oR[i] = aR; oG[i] = aG; oB[i] = aB;
    }

    *(float4*)(out + base)               = make_float4(oR[0], oR[1], oR[2], oR[3]);
    *(float4*)(out + base + P_PLANE)     = make_float4(oG[0], oG[1], oG[2], oG[3]);
    *(float4*)(out + base + 2 * P_PLANE) = make_float4(oB[0], oB[1], oB[2], oB[3]);
}

extern "C" void kernel_launch(void* const* d_in, const int* in_sizes, int n_in,
                              void* d_out, int out_size, void* d_ws, size_t ws_size,
                              hipStream_t stream) {
    const float* lut = (const float*)d_in[0];
    const float* x   = (const float*)d_in[1];
    float* out = (float*)d_out;

    // Capture-safe host-side queries (execute immediately, not stream ops).
    int dev = 0;
    (void)hipGetDevice(&dev);
    int max_shm = 0;
    (void)hipDeviceGetAttribute(&max_shm, hipDeviceAttributeMaxSharedMemoryPerBlock, dev);
    static_assert(SMEM_BYTES == 143748, "lut lds size");
    (void)hipFuncSetAttribute((const void*)apply_lut_lds,
                              hipFuncAttributeMaxDynamicSharedMemorySize, SMEM_BYTES);

    if (max_shm >= SMEM_BYTES && ws_size >= (size_t)SMEM_BYTES) {
        // LDS-resident linear u8 table; 256 persistent blocks x 1024 threads
        // (1 block/CU, LDS-capped), plain (L2-allocating) output stores.
        unsigned int* T = (unsigned int*)d_ws;
        build_lin_u8<<<(LUT_C + 255) / 256, 256, 0, stream>>>(lut, T);
        apply_lut_lds<<<256, 1024, SMEM_BYTES, stream>>>(x, T, out);
    } else {
        __half* T = (__half*)d_ws;
        build_table<<<128, 256, 0, stream>>>(lut, (uint4*)T);
        apply_lut<<<dim3(P_PLANE / (4 * 256), N_IMG), 256, 0, stream>>>(x, T, out);
    }
}

// Round 10
// 185.717 us; speedup vs baseline: 1.1801x; 1.0122x over previous
//
#include <hip/hip_runtime.h>
#include <hip/hip_fp16.h>

#define P_PLANE (1080*1920)          // 2,073,600 pixels per channel plane
#define LUT_C   35937                 // 33*33*33, per-channel LUT stride
#define N_IMG   4
#define SMEM_WORDS 35937
#define SMEM_BYTES (SMEM_WORDS * 4)   // 143,748 B of LDS

typedef float fvec4 __attribute__((ext_vector_type(4)));   // builtin-compatible float4

__device__ __forceinline__ float ub0(unsigned int e) { return (float)(e & 255u); }
__device__ __forceinline__ float ub1(unsigned int e) { return (float)((e >> 8) & 255u); }
__device__ __forceinline__ float ub2(unsigned int e) { return (float)((e >> 16) & 255u); }

// ---------------------------------------------------------------------------
// Build linear u8 table in ws: entry i (= b*1089+g*33+r) packs (r,g,b,0) u8.
// 35937 entries * 4B = 140.4 KB. Quantization err <= 1/510 ~ 2e-3.
// ---------------------------------------------------------------------------
__global__ __launch_bounds__(256) void build_lin_u8(const float* __restrict__ lut,
                                                    unsigned int* __restrict__ T) {
    int i = blockIdx.x * blockDim.x + threadIdx.x;
    if (i >= LUT_C) return;
    unsigned int r = (unsigned int)__float2int_rn(lut[i] * 255.0f);
    unsigned int g = (unsigned int)__float2int_rn(lut[LUT_C + i] * 255.0f);
    unsigned int b = (unsigned int)__float2int_rn(lut[2 * LUT_C + i] * 255.0f);
    T[i] = r | (g << 8) | (b << 16);
}

// ---------------------------------------------------------------------------
// R10 main kernel: R9 body (LDS-resident u8 LUT, pinned phases, one-ahead
// input prefetch, plain stores) + DEFERRED-STORE PIPELINE.
// Theory: on CDNA a VMEM store reads its data VGPRs asynchronously; the
// compiler inserts s_waitcnt on that store before the regs are REDEFINED.
// All prior variants (VGPR 40-56, minimal RA) store vR/vG/vB at the end of
// iteration i and redefine them at the start of i+1 -> every iteration
// tail-waits on its own stores' COMPLETION (policy-independent: R9 null;
// schedule-independent: R2/R4/R5 null; worse under write amplification:
// R1 +25%). Fix: hold outputs in dedicated `held` regs; issue the store at
// the TOP of the NEXT iteration so it ages through a full compute body
// (~thousands of cycles) before `held` is overwritten. Input-load consume
// needs only vmcnt(3) (3 newer stores), never own-store completion.
// ---------------------------------------------------------------------------
__global__ __launch_bounds__(1024, 4) void apply_lut_lds(const float* __restrict__ x,
                                                         const unsigned int* __restrict__ T,
                                                         float* __restrict__ out) {
    extern __shared__ unsigned int s_lut[];
    const int tid = threadIdx.x;

    // Fill LDS: 8984 uint4 + 1 tail word, coalesced.
    {
        const uint4* Tv = (const uint4*)T;
        uint4* sv = (uint4*)s_lut;
        for (int i = tid; i < SMEM_WORDS / 4; i += blockDim.x) sv[i] = Tv[i];
        if (tid == 0) s_lut[SMEM_WORDS - 1] = T[SMEM_WORDS - 1];
    }
    __syncthreads();

    const float inv = (float)(1.0 / (1.000001 / 32.0));   // matches reference f32 rounding
    const float qs = 1.0f / 255.0f;                        // u8 dequant, folded into wb
    const int QPI = P_PLANE / 4;                           // 518,400 quads per image
    const int total = N_IMG * QPI;                         // 2,073,600 quads
    const int G = gridDim.x * blockDim.x;                  // 262,144

    int q = blockIdx.x * blockDim.x + tid;
    if (q >= total) return;

    size_t base;
    {
        int n = q / QPI;
        base = (size_t)n * (3 * P_PLANE) + (size_t)(q - n * QPI) * 4;
    }
    fvec4 r4 = *(const fvec4*)(x + base);
    fvec4 g4 = *(const fvec4*)(x + base + P_PLANE);
    fvec4 b4 = *(const fvec4*)(x + base + 2 * P_PLANE);

    // Deferred-store state: previous iteration's outputs + address.
    fvec4 hR, hG, hB;
    size_t hbase = 0;
    bool have_held = false;

    while (true) {
        // ---- Phase F' (deferred): store PREVIOUS quad's outputs. Issued at
        // the top so the store ages through this whole body before `held` is
        // overwritten at the bottom -> the overwrite-hazard waitcnt is free.
        if (have_held) {
            *(fvec4*)(out + hbase)               = hR;
            *(fvec4*)(out + hbase + P_PLANE)     = hG;
            *(fvec4*)(out + hbase + 2 * P_PLANE) = hB;
        }

        // ---- Phase A: idx + fracs for 4 pixels (consumes current loads;
        // needs vmcnt(3): 3 newer stores above may stay in flight).
        int   idx[4];
        float fr[4], fg[4], fb[4];
#pragma unroll
        for (int i = 0; i < 4; ++i) {
            float tr = r4[i] * inv, tg = g4[i] * inv, tb = b4[i] * inv;
            float fr_ = floorf(tr), fg_ = floorf(tg), fb_ = floorf(tb);
            fr[i] = tr - fr_; fg[i] = tg - fg_; fb[i] = tb - fb_;   // fracs BEFORE clip
            int ri = min(max((int)fr_, 0), 31);
            int gi = min(max((int)fg_, 0), 31);
            int bi = min(max((int)fb_, 0), 31);
            idx[i] = bi * 1089 + gi * 33 + ri;
        }

        // ---- Phase B: issue ALL 16 ds_read2-class gathers.
        unsigned int e[4][8];
#pragma unroll
        for (int i = 0; i < 4; ++i) {
            int i0 = idx[i];
            int i1 = idx[i] + 1089;
            e[i][0] = s_lut[i0];       e[i][1] = s_lut[i0 + 1];
            e[i][2] = s_lut[i0 + 33];  e[i][3] = s_lut[i0 + 34];
            e[i][4] = s_lut[i1];       e[i][5] = s_lut[i1 + 1];
            e[i][6] = s_lut[i1 + 33];  e[i][7] = s_lut[i1 + 34];
        }

        // ---- Phase C: issue NEXT iteration's global loads (in the DS shadow).
        int qn = q + G;
        const bool more = (qn < total);
        int qc = more ? qn : q;                 // branchless tail: re-read q (L1-hot)
        size_t nbase;
        {
            int n = qc / QPI;
            nbase = (size_t)n * (3 * P_PLANE) + (size_t)(qc - n * QPI) * 4;
        }
        fvec4 nr4 = *(const fvec4*)(x + nbase);
        fvec4 ng4 = *(const fvec4*)(x + nbase + P_PLANE);
        fvec4 nb4 = *(const fvec4*)(x + nbase + 2 * P_PLANE);

        // ---- FENCE: keep issue phases above, consume phases below.
        __builtin_amdgcn_sched_barrier(0);

        // ---- Phase D: weights (pure VALU, fills the DS shadow).
        float w[4][8];
#pragma unroll
        for (int i = 0; i < 4; ++i) {
            float wr1 = fr[i], wr0 = 1.0f - fr[i];
            float wg1 = fg[i], wg0 = 1.0f - fg[i];
            float wb1 = fb[i] * qs, wb0 = (1.0f - fb[i]) * qs;   // fold 1/255
            float w00 = wb0 * wg0, w01 = wb0 * wg1, w10 = wb1 * wg0, w11 = wb1 * wg1;
            w[i][0] = w00 * wr0; w[i][1] = w00 * wr1;
            w[i][2] = w01 * wr0; w[i][3] = w01 * wr1;
            w[i][4] = w10 * wr0; w[i][5] = w10 * wr1;
            w[i][6] = w11 * wr0; w[i][7] = w11 * wr1;
        }

        // ---- Phase E: interpolate (ONE lgkm wait, then 96 FMAs).
        fvec4 vR, vG, vB;
#pragma unroll
        for (int i = 0; i < 4; ++i) {
            float aR = w[i][0] * ub0(e[i][0]);
            float aG = w[i][0] * ub1(e[i][0]);
            float aB = w[i][0] * ub2(e[i][0]);
#pragma unroll
            for (int k = 1; k < 8; ++k) {
                aR = fmaf(w[i][k], ub0(e[i][k]), aR);
                aG = fmaf(w[i][k], ub1(e[i][k]), aG);
                aB = fmaf(w[i][k], ub2(e[i][k]), aB);
            }
            vR[i] = aR; vG[i] = aG; vB[i] = aB;
        }

        // ---- Rotate: hold this quad's outputs; overwrite of the PREVIOUS
        // held values happens here, a full body after their store issued.
        hR = vR; hG = vG; hB = vB; hbase = base; have_held = true;

        if (!more) break;
        q = qn; base = nbase;
        r4 = nr4; g4 = ng4; b4 = nb4;
    }

    // ---- Epilogue: store the final held quad.
    *(fvec4*)(out + hbase)               = hR;
    *(fvec4*)(out + hbase + P_PLANE)     = hG;
    *(fvec4*)(out + hbase + 2 * P_PLANE) = hB;
}

// ===========================================================================
// Fallback path (R0, proven): fp16 cell-duplicated table + global gathers.
// ===========================================================================
__global__ __launch_bounds__(256) void build_table(const float* __restrict__ lut,
                                                   uint4* __restrict__ T) {
    int cell = blockIdx.x * blockDim.x + threadIdx.x;   // 0 .. 32767
    int rid = cell & 31;
    int gid = (cell >> 5) & 31;
    int bid = cell >> 10;
    const float* b0 = lut + bid * 1089 + gid * 33 + rid;
    uint4 q[4];
    __half* h = (__half*)q;
#pragma unroll
    for (int k = 0; k < 8; ++k) {
        int off = (k >> 2) * 1089 + ((k >> 1) & 1) * 33 + (k & 1);
        h[k * 4 + 0] = __float2half(b0[off]);
        h[k * 4 + 1] = __float2half(b0[LUT_C + off]);
        h[k * 4 + 2] = __float2half(b0[2 * LUT_C + off]);
        h[k * 4 + 3] = __float2half(0.0f);
    }
    uint4* dst = T + (size_t)cell * 4;
    dst[0] = q[0]; dst[1] = q[1]; dst[2] = q[2]; dst[3] = q[3];
}

__device__ __forceinline__ void acc_chunk(const uint4& q, float wA, float wB,
                                          float& aR, float& aG, float& aB) {
    const __half* h = (const __half*)&q;
    aR = fmaf(wA, __half2float(h[0]), fmaf(wB, __half2float(h[4]), aR));
    aG = fmaf(wA, __half2float(h[1]), fmaf(wB, __half2float(h[5]), aG));
    aB = fmaf(wA, __half2float(h[2]), fmaf(wB, __half2float(h[6]), aB));
}

__global__ __launch_bounds__(256) void apply_lut(const float* __restrict__ x,
                                                 const __half* __restrict__ T,
                                                 float* __restrict__ out) {
    const float inv = (float)(1.0 / (1.000001 / 32.0));
    int n  = blockIdx.y;
    int i4 = blockIdx.x * blockDim.x + threadIdx.x;
    size_t base = (size_t)n * 3 * P_PLANE + (size_t)i4 * 4;

    float4 r4 = *(const float4*)(x + base);
    float4 g4 = *(const float4*)(x + base + P_PLANE);
    float4 b4 = *(const float4*)(x + base + 2 * P_PLANE);

    float r[4] = {r4.x, r4.y, r4.z, r4.w};
    float g[4] = {g4.x, g4.y, g4.z, g4.w};
    float b[4] = {b4.x, b4.y, b4.z, b4.w};
    float oR[4], oG[4], oB[4];

#pragma unroll
    for (int i = 0; i < 4; ++i) {
        float tr = r[i] * inv;
        float tg = g[i] * inv;
        float tb = b[i] * inv;
        float fr_ = floorf(tr), fg_ = floorf(tg), fb_ = floorf(tb);
        float fr = tr - fr_, fg = tg - fg_, fb = tb - fb_;
        int ri = min(max((int)fr_, 0), 31);
        int gi = min(max((int)fg_, 0), 31);
        int bi = min(max((int)fb_, 0), 31);

        const uint4* cp = (const uint4*)(T + ((size_t)(((bi << 5) | gi) << 5 | ri) << 5));
        uint4 q0 = cp[0], q1 = cp[1], q2 = cp[2], q3 = cp[3];

        float wr1 = fr, wr0 = 1.0f - fr;
        float wg1 = fg, wg0 = 1.0f - fg;
        float wb1 = fb, wb0 = 1.0f - fb;
        float w00 = wb0 * wg0, w01 = wb0 * wg1, w10 = wb1 * wg0, w11 = wb1 * wg1;

        float aR = 0.f, aG = 0.f, aB = 0.f;
        acc_chunk(q0, w00 * wr0, w00 * wr1, aR, aG, aB);
        acc_chunk(q1, w01 * wr0, w01 * wr1, aR, aG, aB);
        acc_chunk(q2, w10 * wr0, w10 * wr1, aR, aG, aB);
        acc_chunk(q3, w11 * wr0, w11 * wr1, aR, aG, aB);

        oR[i] = aR; oG[i] = aG; oB[i] = aB;
    }

    *(float4*)(out + base)               = make_float4(oR[0], oR[1], oR[2], oR[3]);
    *(float4*)(out + base + P_PLANE)     = make_float4(oG[0], oG[1], oG[2], oG[3]);
    *(float4*)(out + base + 2 * P_PLANE) = make_float4(oB[0], oB[1], oB[2], oB[3]);
}

extern "C" void kernel_launch(void* const* d_in, const int* in_sizes, int n_in,
                              void* d_out, int out_size, void* d_ws, size_t ws_size,
                              hipStream_t stream) {
    const float* lut = (const float*)d_in[0];
    const float* x   = (const float*)d_in[1];
    float* out = (float*)d_out;

    // Capture-safe host-side queries (execute immediately, not stream ops).
    int dev = 0;
    (void)hipGetDevice(&dev);
    int max_shm = 0;
    (void)hipDeviceGetAttribute(&max_shm, hipDeviceAttributeMaxSharedMemoryPerBlock, dev);
    static_assert(SMEM_BYTES == 143748, "lut lds size");
    (void)hipFuncSetAttribute((const void*)apply_lut_lds,
                              hipFuncAttributeMaxDynamicSharedMemorySize, SMEM_BYTES);

    if (max_shm >= SMEM_BYTES && ws_size >= (size_t)SMEM_BYTES) {
        // LDS-resident linear u8 table; 256 persistent blocks x 1024 threads
        // (1 block/CU, LDS-capped), deferred-store pipeline.
        unsigned int* T = (unsigned int*)d_ws;
        build_lin_u8<<<(LUT_C + 255) / 256, 256, 0, stream>>>(lut, T);
        apply_lut_lds<<<256, 1024, SMEM_BYTES, stream>>>(x, T, out);
    } else {
        __half* T = (__half*)d_ws;
        build_table<<<128, 256, 0, stream>>>(lut, (uint4*)T);
        apply_lut<<<dim3(P_PLANE / (4 * 256), N_IMG), 256, 0, stream>>>(x, T, out);
    }
}